// Round 16
// baseline (251.572 us; speedup 1.0000x reference)
//
#include <hip/hip_runtime.h>
#include <hip/hip_fp16.h>
#include <math.h>

#define VOCAB_ 50000
#define B_ 32
#define Q_ 16
#define D_ 10
#define L_ 1000
#define E_ 300

#define NS_  8          // l-splits per (b,d) for f16 main -> 2560 blocks
#define TPB_ 128        // terms per block (two waves share one term)
#define RP_  320        // padded fp16 row stride: 640 B = 5 x 128B lines
#define G8_  40         // 8-elem groups per padded row (40*8 = 320)
#define GSPL_ 24        // line-aligned split: groups [0,24) = lines 0-2,
                        //                     groups [24,40) = lines 3-4
#define CVU_ (VOCAB_ * G8_)   // cvt work units (one 16B half8 store each)

typedef _Float16 half8 __attribute__((ext_vector_type(8)));
typedef _Float16 h2_t  __attribute__((ext_vector_type(2)));

#if __has_builtin(__builtin_amdgcn_fdot2)
#define DOT2(a, b, c) __builtin_amdgcn_fdot2((a), (b), (c), false)
#else
#define DOT2(a, b, c) fmaf((float)(a)[0], (float)(b)[0], \
                      fmaf((float)(a)[1], (float)(b)[1], (c)))
#endif
#define SV2(v, i) __builtin_shufflevector((v), (v), 2*(i), 2*(i)+1)

// ---------------------------------------------------------------------------
// Kernel 0 (cvt): fp32 embedding -> fp16 table, row-padded to 320 elems
// (pad=0). One thread per 8-elem group: 2x float4 load + one 16B store.
// ---------------------------------------------------------------------------
__global__ __launch_bounds__(256) void drmm_cvt(
    const float* __restrict__ emb, _Float16* __restrict__ emb16)
{
    const int u = blockIdx.x * 256 + threadIdx.x;
    if (u >= CVU_) return;
    const int row = u / G8_;
    const int g   = u - row * G8_;
    half8 o;
    if (g < 37) {
        const float* src = emb + (size_t)row * E_ + 8 * g;   // 16B-aligned
        const float4 a = *(const float4*)src;
        const float4 c = *(const float4*)(src + 4);
        o[0] = (_Float16)a.x; o[1] = (_Float16)a.y;
        o[2] = (_Float16)a.z; o[3] = (_Float16)a.w;
        o[4] = (_Float16)c.x; o[5] = (_Float16)c.y;
        o[6] = (_Float16)c.z; o[7] = (_Float16)c.w;
    } else if (g == 37) {          // elems 296..299 + 4 zero pads
        const float4 a = *(const float4*)(emb + (size_t)row * E_ + 296);
        o[0] = (_Float16)a.x; o[1] = (_Float16)a.y;
        o[2] = (_Float16)a.z; o[3] = (_Float16)a.w;
        o[4] = (_Float16)0.f; o[5] = (_Float16)0.f;
        o[6] = (_Float16)0.f; o[7] = (_Float16)0.f;
    } else {                       // groups 38,39: all zero (no read)
#pragma unroll
        for (int i = 0; i < 8; ++i) o[i] = (_Float16)0.f;
    }
    *(half8*)(emb16 + (size_t)row * RP_ + 8 * g) = o;
}

// ---------------------------------------------------------------------------
// Kernel 1 (prep): per-batch query gather -> gate logits -> softmax,
// query norms, and score init with the affine constant.  (fp32 exact)
// ---------------------------------------------------------------------------
__global__ __launch_bounds__(256) void drmm_prep(
    const int* __restrict__ bq, const float* __restrict__ emb,
    const float* __restrict__ gate_w, const float* __restrict__ gate_b,
    const float* __restrict__ b1, const float* __restrict__ w2,
    const float* __restrict__ b2, const float* __restrict__ out_w,
    const float* __restrict__ out_b,
    float* __restrict__ wqBuf, float* __restrict__ nqBuf,
    float* __restrict__ score)
{
    const int b = blockIdx.x;
    const int tid = threadIdx.x;
    const int w = tid >> 6, lane = tid & 63;
    __shared__ float logits[Q_];

#pragma unroll
    for (int i = 0; i < 4; ++i) {
        const int q = w * 4 + i;
        const int tok = bq[b * Q_ + q];
        const float* row = emb + (size_t)tok * E_;
        float4 dv = *(const float4*)(row + 4 * lane);
        float4 gv = *(const float4*)(gate_w + 4 * lane);
        float pd = dv.x * gv.x + dv.y * gv.y + dv.z * gv.z + dv.w * gv.w;
        float ps = dv.x * dv.x + dv.y * dv.y + dv.z * dv.z + dv.w * dv.w;
        if (lane < 11) {
            float4 dv2 = *(const float4*)(row + 256 + 4 * lane);
            float4 gv2 = *(const float4*)(gate_w + 256 + 4 * lane);
            pd += dv2.x * gv2.x + dv2.y * gv2.y + dv2.z * gv2.z + dv2.w * gv2.w;
            ps += dv2.x * dv2.x + dv2.y * dv2.y + dv2.z * dv2.z + dv2.w * dv2.w;
        }
#pragma unroll
        for (int off = 32; off > 0; off >>= 1) {
            pd += __shfl_xor(pd, off);
            ps += __shfl_xor(ps, off);
        }
        if (lane == 0) {
            logits[q] = pd + gate_b[0];
            nqBuf[b * Q_ + q] = sqrtf(ps);
        }
    }
    __syncthreads();

    if (tid == 0) {
        float m = -1e30f;
        for (int q = 0; q < Q_; ++q) m = fmaxf(m, logits[q]);
        float e[Q_];
        float s = 0.f;
        for (int q = 0; q < Q_; ++q) { e[q] = expf(logits[q] - m); s += e[q]; }
        const float sc = out_w[0] * w2[0] / s;
        for (int q = 0; q < Q_; ++q) wqBuf[b * Q_ + q] = e[q] * sc;
    }
    if (tid < D_)
        score[b * D_ + tid] = out_w[0] * (w2[0] * b1[0] + b2[0]) + out_b[0];
}

// ---------------------------------------------------------------------------
// Kernel 2 (main, fp16): TWO waves per doc term, split at LINE granularity:
// even wave reads groups [0,24) (lines 0-2 of the 640B row), odd wave
// [24,40) (lines 3-4) -- disjoint 128B lines, so FETCH stays flat while
// resident waves/CU go 20 -> 32 (grid 2560x256, launch_bounds(256,8)).
// The delivered L3->L2 rate scaled with occupancy across R3/R15 (1.48 TB/s
// @28% vs 3.1 @56%); this buys that rate without R3's sub-line FETCH
// inflation. Halves combine via part[128][17] LDS (stride 17, conflict-
// free). Queries fp16 in LDS; inner loop pure v_dot2_f32_f16.
// ---------------------------------------------------------------------------
__global__ __launch_bounds__(256, 8) void drmm_main_f16(
    const int* __restrict__ bq, const int* __restrict__ bdocs,
    const _Float16* __restrict__ emb16, const float* __restrict__ w1,
    const float* __restrict__ wqBuf, const float* __restrict__ nqBuf,
    float* __restrict__ score)
{
    const int ls = blockIdx.x;   // 0..7 (128 terms each; last has 104)
    const int d  = blockIdx.y;
    const int b  = blockIdx.z;
    const int tid  = threadIdx.x;
    const int lane = tid & 63;
    const int w = __builtin_amdgcn_readfirstlane(tid >> 6);   // 0..3, uniform
    const int h = w & 1;                    // row-half (wave-uniform)
    const int slot = (w >> 1) * 64 + lane;  // term slot 0..127

    __shared__ half8 qt[Q_ * G8_];      // 10,240 B  (qt[q*40+g])
    __shared__ float part[TPB_][17];    // 8,704 B   (acc0..15, sq)
    __shared__ float wsum[4];

    for (int u = tid; u < Q_ * G8_; u += 256) {
        const int q = u / G8_;
        const int g = u - q * G8_;
        qt[u] = *(const half8*)(emb16 + (size_t)bq[b * Q_ + q] * RP_ + 8 * g);
    }
    __syncthreads();

    const int l = ls * TPB_ + slot;
    const bool active = (l < L_);
    // inactive slots stream the last valid term's row; results discarded
    const int tok = bdocs[(b * D_ + d) * L_ + min(l, L_ - 1)];
    const _Float16* drow = emb16 + (size_t)tok * RP_;

    float acc[Q_];
#pragma unroll
    for (int q = 0; q < Q_; ++q) acc[q] = 0.f;
    float sq = 0.f;

    // Wave-uniform branch (s_cbranch): compile-time group bounds per half.
    if (h == 0) {
#pragma unroll 8
        for (int g = 0; g < GSPL_; ++g) {
            const half8 dv = *(const half8*)(drow + 8 * g);
            const h2_t d0 = SV2(dv, 0), d1 = SV2(dv, 1),
                       d2 = SV2(dv, 2), d3 = SV2(dv, 3);
            sq = DOT2(d0, d0, DOT2(d1, d1, DOT2(d2, d2, DOT2(d3, d3, sq))));
#pragma unroll
            for (int q = 0; q < Q_; ++q) {
                const half8 qv = qt[q * G8_ + g];
                float t = DOT2(SV2(qv, 0), d0, acc[q]);
                t       = DOT2(SV2(qv, 1), d1, t);
                t       = DOT2(SV2(qv, 2), d2, t);
                acc[q]  = DOT2(SV2(qv, 3), d3, t);
            }
        }
    } else {
#pragma unroll 8
        for (int g = GSPL_; g < G8_; ++g) {
            const half8 dv = *(const half8*)(drow + 8 * g);
            const h2_t d0 = SV2(dv, 0), d1 = SV2(dv, 1),
                       d2 = SV2(dv, 2), d3 = SV2(dv, 3);
            sq = DOT2(d0, d0, DOT2(d1, d1, DOT2(d2, d2, DOT2(d3, d3, sq))));
#pragma unroll
            for (int q = 0; q < Q_; ++q) {
                const half8 qv = qt[q * G8_ + g];
                float t = DOT2(SV2(qv, 0), d0, acc[q]);
                t       = DOT2(SV2(qv, 1), d1, t);
                t       = DOT2(SV2(qv, 2), d2, t);
                acc[q]  = DOT2(SV2(qv, 3), d3, t);
            }
        }
    }

    // Combine halves: odd wave publishes, even wave finishes.
    if (h == 1) {
#pragma unroll
        for (int q = 0; q < Q_; ++q) part[slot][q] = acc[q];
        part[slot][16] = sq;
    }
    __syncthreads();

    float total = 0.f;
    if (h == 0 && active) {
        const float nd = sqrtf(sq + part[slot][16]);
        const float w10 = w1[0], w11 = w1[1], w12 = w1[2],
                    w13 = w1[3], w14 = w1[4];
#pragma unroll
        for (int q = 0; q < Q_; ++q) {
            const float nqv = nqBuf[b * Q_ + q];   // uniform -> s_load
            const float wqv = wqBuf[b * Q_ + q];
            const float denom = fmaxf(nqv * nd, 1e-8f);
            const float a = acc[q] + part[slot][q];
            // bins: [-1,-.5) [-.5,0) [0,.5) [.5,1) [1,1]; outside -> 0
            const float wv = (a < -denom)        ? 0.f
                           : (a < -0.5f * denom) ? w10
                           : (a < 0.f)           ? w11
                           : (a < 0.5f * denom)  ? w12
                           : (a < denom)         ? w13
                           : (a <= denom)        ? w14
                                                 : 0.f;
            total = fmaf(wqv, wv, total);
        }
    }

#pragma unroll
    for (int off = 32; off > 0; off >>= 1) total += __shfl_xor(total, off);
    if (lane == 0) wsum[w] = total;
    __syncthreads();
    if (tid == 0)
        atomicAdd(&score[b * D_ + d], wsum[0] + wsum[1] + wsum[2] + wsum[3]);
}

// ---------------------------------------------------------------------------
// Kernel 2 fallback (fp32, used only if ws can't hold the fp16 table):
// direct fp32 row streaming + fp32 queries in LDS (R15 structure).
// ---------------------------------------------------------------------------
__global__ __launch_bounds__(256, 4) void drmm_main_f32(
    const int* __restrict__ bq, const int* __restrict__ bdocs,
    const float* __restrict__ emb, const float* __restrict__ w1,
    const float* __restrict__ wqBuf, const float* __restrict__ nqBuf,
    float* __restrict__ score)
{
    const int ls = blockIdx.x;   // 0..3, 250 terms each
    const int d  = blockIdx.y;
    const int b  = blockIdx.z;
    const int tid  = threadIdx.x;
    const int lane = tid & 63;
    const int w    = tid >> 6;

    __shared__ float4 qt[Q_ * 76];    // chunks 0..74 row, 75 zeros
    __shared__ float wsum[4];

    for (int u = tid; u < Q_ * 76; u += 256) {
        const int q = u / 76;
        const int c = u - q * 76;
        float4 v = make_float4(0.f, 0.f, 0.f, 0.f);
        if (c < 75)
            v = *(const float4*)(emb + (size_t)bq[b * Q_ + q] * E_ + 4 * c);
        qt[u] = v;
    }
    __syncthreads();

    const int tok = bdocs[(b * D_ + d) * L_ + ls * 250 + min(tid, 249)];
    const float* drow = emb + (size_t)tok * E_;

    float acc[Q_];
#pragma unroll
    for (int q = 0; q < Q_; ++q) acc[q] = 0.f;
    float sqA = 0.f, sqB = 0.f;

#pragma unroll 9
    for (int g = 0; g < 37; ++g) {
        const float4 a  = *(const float4*)(drow + 8 * g);
        const float4 c4 = *(const float4*)(drow + 8 * g + 4);
        sqA = fmaf(a.x, a.x, fmaf(a.z, a.z, fmaf(c4.x, c4.x, fmaf(c4.z, c4.z, sqA))));
        sqB = fmaf(a.y, a.y, fmaf(a.w, a.w, fmaf(c4.y, c4.y, fmaf(c4.w, c4.w, sqB))));
#pragma unroll
        for (int q = 0; q < Q_; ++q) {
            const float4 qa = qt[q * 76 + 2 * g];
            const float4 qb = qt[q * 76 + 2 * g + 1];
            float t0 = fmaf(a.x, qa.x, fmaf(a.y, qa.y,
                       fmaf(a.z, qa.z, fmaf(a.w, qa.w, acc[q]))));
            acc[q]   = fmaf(c4.x, qb.x, fmaf(c4.y, qb.y,
                       fmaf(c4.z, qb.z, fmaf(c4.w, qb.w, t0))));
        }
    }
    {   // tail: elems 296..299
        const float4 a = *(const float4*)(drow + 296);
        sqA = fmaf(a.x, a.x, fmaf(a.z, a.z, sqA));
        sqB = fmaf(a.y, a.y, fmaf(a.w, a.w, sqB));
#pragma unroll
        for (int q = 0; q < Q_; ++q) {
            const float4 qa = qt[q * 76 + 74];
            acc[q] = fmaf(a.x, qa.x, fmaf(a.y, qa.y,
                     fmaf(a.z, qa.z, fmaf(a.w, qa.w, acc[q]))));
        }
    }

    float total = 0.f;
    if (tid < 250) {
        const float nd = sqrtf(sqA + sqB);
        const float w10 = w1[0], w11 = w1[1], w12 = w1[2],
                    w13 = w1[3], w14 = w1[4];
#pragma unroll
        for (int q = 0; q < Q_; ++q) {
            const float nqv = nqBuf[b * Q_ + q];
            const float wqv = wqBuf[b * Q_ + q];
            const float denom = fmaxf(nqv * nd, 1e-8f);
            const float a = acc[q];
            const float wv = (a < -denom)        ? 0.f
                           : (a < -0.5f * denom) ? w10
                           : (a < 0.f)           ? w11
                           : (a < 0.5f * denom)  ? w12
                           : (a < denom)         ? w13
                           : (a <= denom)        ? w14
                                                 : 0.f;
            total = fmaf(wqv, wv, total);
        }
    }

#pragma unroll
    for (int off = 32; off > 0; off >>= 1) total += __shfl_xor(total, off);
    if (lane == 0) wsum[w] = total;
    __syncthreads();
    if (tid == 0)
        atomicAdd(&score[b * D_ + d], wsum[0] + wsum[1] + wsum[2] + wsum[3]);
}

extern "C" void kernel_launch(void* const* d_in, const int* in_sizes, int n_in,
                              void* d_out, int out_size, void* d_ws, size_t ws_size,
                              hipStream_t stream)
{
    const int*   bq     = (const int*)d_in[0];
    const int*   bdocs  = (const int*)d_in[1];
    const float* emb    = (const float*)d_in[2];
    const float* gate_w = (const float*)d_in[3];
    const float* gate_b = (const float*)d_in[4];
    const float* w1     = (const float*)d_in[5];
    const float* b1     = (const float*)d_in[6];
    const float* w2     = (const float*)d_in[7];
    const float* b2     = (const float*)d_in[8];
    const float* out_w  = (const float*)d_in[9];
    const float* out_b  = (const float*)d_in[10];

    float* score = (float*)d_out;
    float* wqBuf = (float*)d_ws;              // 512 floats
    float* nqBuf = wqBuf + B_ * Q_;           // 512 floats (first 4 KiB)

    const size_t e16_off   = 4096;
    const size_t e16_bytes = (size_t)VOCAB_ * RP_ * sizeof(_Float16);  // 32 MB
    const bool useF16 = ws_size >= e16_off + e16_bytes;
    _Float16* emb16 = (_Float16*)((char*)d_ws + e16_off);

    if (useF16)
        drmm_cvt<<<dim3((CVU_ + 255) / 256), dim3(256), 0, stream>>>(emb, emb16);

    drmm_prep<<<dim3(B_), dim3(256), 0, stream>>>(
        bq, emb, gate_w, gate_b, b1, w2, b2, out_w, out_b, wqBuf, nqBuf, score);

    if (useF16)
        drmm_main_f16<<<dim3(NS_, D_, B_), dim3(256), 0, stream>>>(
            bq, bdocs, emb16, w1, wqBuf, nqBuf, score);
    else
        drmm_main_f32<<<dim3(4, D_, B_), dim3(256), 0, stream>>>(
            bq, bdocs, emb, w1, wqBuf, nqBuf, score);
}

// Round 17
// 210.380 us; speedup vs baseline: 1.1958x; 1.1958x over previous
//
#include <hip/hip_runtime.h>
#include <hip/hip_fp16.h>
#include <math.h>

#define VOCAB_ 50000
#define B_ 32
#define Q_ 16
#define D_ 10
#define L_ 1000
#define E_ 300

#define NR_    8        // token ranges == XCDs; range = tok / 6250
#define RANGE_ (VOCAB_ / NR_)   // 6250 rows = 4 MB fp16 = one XCD L2
#define RP_  320        // padded fp16 row stride: 640 B = 5 x 128B lines
#define G8_  40         // 8-elem groups per padded row (40*8 = 320)
#define CVU_ (VOCAB_ * G8_)   // cvt work units (one 16B half8 store each)

typedef _Float16 half8 __attribute__((ext_vector_type(8)));
typedef _Float16 h2_t  __attribute__((ext_vector_type(2)));

#if __has_builtin(__builtin_amdgcn_fdot2)
#define DOT2(a, b, c) __builtin_amdgcn_fdot2((a), (b), (c), false)
#else
#define DOT2(a, b, c) fmaf((float)(a)[0], (float)(b)[0], \
                      fmaf((float)(a)[1], (float)(b)[1], (c)))
#endif
#define SV2(v, i) __builtin_shufflevector((v), (v), 2*(i), 2*(i)+1)

// ---------------------------------------------------------------------------
// Kernel 0 (cvt): fp32 embedding -> fp16 table, row-padded to 320 elems
// (pad=0). One thread per 8-elem group: 2x float4 load + one 16B store.
// ---------------------------------------------------------------------------
__global__ __launch_bounds__(256) void drmm_cvt(
    const float* __restrict__ emb, _Float16* __restrict__ emb16)
{
    const int u = blockIdx.x * 256 + threadIdx.x;
    if (u >= CVU_) return;
    const int row = u / G8_;
    const int g   = u - row * G8_;
    half8 o;
    if (g < 37) {
        const float* src = emb + (size_t)row * E_ + 8 * g;   // 16B-aligned
        const float4 a = *(const float4*)src;
        const float4 c = *(const float4*)(src + 4);
        o[0] = (_Float16)a.x; o[1] = (_Float16)a.y;
        o[2] = (_Float16)a.z; o[3] = (_Float16)a.w;
        o[4] = (_Float16)c.x; o[5] = (_Float16)c.y;
        o[6] = (_Float16)c.z; o[7] = (_Float16)c.w;
    } else if (g == 37) {          // elems 296..299 + 4 zero pads
        const float4 a = *(const float4*)(emb + (size_t)row * E_ + 296);
        o[0] = (_Float16)a.x; o[1] = (_Float16)a.y;
        o[2] = (_Float16)a.z; o[3] = (_Float16)a.w;
        o[4] = (_Float16)0.f; o[5] = (_Float16)0.f;
        o[6] = (_Float16)0.f; o[7] = (_Float16)0.f;
    } else {                       // groups 38,39: all zero (no read)
#pragma unroll
        for (int i = 0; i < 8; ++i) o[i] = (_Float16)0.f;
    }
    *(half8*)(emb16 + (size_t)row * RP_ + 8 * g) = o;
}

// ---------------------------------------------------------------------------
// Kernel 1 (prep): per-batch query gather -> gate logits -> softmax,
// query norms, and score init with the affine constant.  (fp32 exact)
// ---------------------------------------------------------------------------
__global__ __launch_bounds__(256) void drmm_prep(
    const int* __restrict__ bq, const float* __restrict__ emb,
    const float* __restrict__ gate_w, const float* __restrict__ gate_b,
    const float* __restrict__ b1, const float* __restrict__ w2,
    const float* __restrict__ b2, const float* __restrict__ out_w,
    const float* __restrict__ out_b,
    float* __restrict__ wqBuf, float* __restrict__ nqBuf,
    float* __restrict__ score)
{
    const int b = blockIdx.x;
    const int tid = threadIdx.x;
    const int w = tid >> 6, lane = tid & 63;
    __shared__ float logits[Q_];

#pragma unroll
    for (int i = 0; i < 4; ++i) {
        const int q = w * 4 + i;
        const int tok = bq[b * Q_ + q];
        const float* row = emb + (size_t)tok * E_;
        float4 dv = *(const float4*)(row + 4 * lane);
        float4 gv = *(const float4*)(gate_w + 4 * lane);
        float pd = dv.x * gv.x + dv.y * gv.y + dv.z * gv.z + dv.w * gv.w;
        float ps = dv.x * dv.x + dv.y * dv.y + dv.z * dv.z + dv.w * dv.w;
        if (lane < 11) {
            float4 dv2 = *(const float4*)(row + 256 + 4 * lane);
            float4 gv2 = *(const float4*)(gate_w + 256 + 4 * lane);
            pd += dv2.x * gv2.x + dv2.y * gv2.y + dv2.z * gv2.z + dv2.w * gv2.w;
            ps += dv2.x * dv2.x + dv2.y * dv2.y + dv2.z * dv2.z + dv2.w * dv2.w;
        }
#pragma unroll
        for (int off = 32; off > 0; off >>= 1) {
            pd += __shfl_xor(pd, off);
            ps += __shfl_xor(ps, off);
        }
        if (lane == 0) {
            logits[q] = pd + gate_b[0];
            nqBuf[b * Q_ + q] = sqrtf(ps);
        }
    }
    __syncthreads();

    if (tid == 0) {
        float m = -1e30f;
        for (int q = 0; q < Q_; ++q) m = fmaxf(m, logits[q]);
        float e[Q_];
        float s = 0.f;
        for (int q = 0; q < Q_; ++q) { e[q] = expf(logits[q] - m); s += e[q]; }
        const float sc = out_w[0] * w2[0] / s;
        for (int q = 0; q < Q_; ++q) wqBuf[b * Q_ + q] = e[q] * sc;
    }
    if (tid < D_)
        score[b * D_ + tid] = out_w[0] * (w2[0] * b1[0] + b2[0]) + out_b[0];
}

// ---------------------------------------------------------------------------
// Kernel 2 (main, fp16, XCD token-affinity): block (r,d,b) handles ONLY the
// ~125 terms of (b,d) whose token falls in range r = tok/6250 (4 MB of the
// fp16 table). With grid (8,10,32), linear block id % 8 == r, which the HW
// round-robins onto XCD r -> each XCD's L2 holds exactly its range after
// compulsory fill; row re-visits (avg 6.4x per row) become STRUCTURAL L2
// hits instead of temporal-locality rent (the R16 lesson: that rent dies
// with occupancy). Scan+LDS-compact (order-free, sum is commutative), then
// the R15 dot2 inner loop on the dense list. Worst-case skew (all 1000
// terms in one range) handled by the k-loop. One atomic per block.
// ---------------------------------------------------------------------------
__global__ __launch_bounds__(128, 4) void drmm_main_f16(
    const int* __restrict__ bq, const int* __restrict__ bdocs,
    const _Float16* __restrict__ emb16, const float* __restrict__ w1,
    const float* __restrict__ wqBuf, const float* __restrict__ nqBuf,
    float* __restrict__ score)
{
    const int r = blockIdx.x;    // token range == XCD (linear bid % 8)
    const int d = blockIdx.y;
    const int b = blockIdx.z;
    const int tid  = threadIdx.x;   // 0..127 (2 waves)
    const int lane = tid & 63;
    const int w    = tid >> 6;

    __shared__ half8 qt[Q_ * G8_];        // 10,240 B (qt[q*40+g])
    __shared__ unsigned int list[L_];     // 4,000 B  (token per match)
    __shared__ int cnt;
    __shared__ float wsum[2];

    if (tid == 0) cnt = 0;
    for (int u = tid; u < Q_ * G8_; u += 128) {   // 5 units/thread
        const int q = u / G8_;
        const int g = u - q * G8_;
        qt[u] = *(const half8*)(emb16 + (size_t)bq[b * Q_ + q] * RP_ + 8 * g);
    }
    __syncthreads();   // cnt=0 visible before appends; qt ready

    // scan this (b,d)'s 1000 tokens; compact range-r matches (coalesced)
    const int base = (b * D_ + d) * L_;
    for (int l = tid; l < L_; l += 128) {
        const int tok = bdocs[base + l];
        if (tok / RANGE_ == r) {
            const int pos = atomicAdd(&cnt, 1);
            list[pos] = (unsigned)tok;
        }
    }
    __syncthreads();
    const int n = cnt;

    const float w10 = w1[0], w11 = w1[1], w12 = w1[2],
                w13 = w1[3], w14 = w1[4];

    float total = 0.f;
    for (int k = tid; k < n; k += 128) {
        const _Float16* drow = emb16 + (size_t)list[k] * RP_;

        float acc[Q_];
#pragma unroll
        for (int q = 0; q < Q_; ++q) acc[q] = 0.f;
        float sq = 0.f;

#pragma unroll 8
        for (int g = 0; g < G8_; ++g) {
            const half8 dv = *(const half8*)(drow + 8 * g);   // 16B load
            const h2_t d0 = SV2(dv, 0), d1 = SV2(dv, 1),
                       d2 = SV2(dv, 2), d3 = SV2(dv, 3);
            sq = DOT2(d0, d0, DOT2(d1, d1, DOT2(d2, d2, DOT2(d3, d3, sq))));
#pragma unroll
            for (int q = 0; q < Q_; ++q) {
                const half8 qv = qt[q * G8_ + g];     // uniform: broadcast
                float t = DOT2(SV2(qv, 0), d0, acc[q]);
                t       = DOT2(SV2(qv, 1), d1, t);
                t       = DOT2(SV2(qv, 2), d2, t);
                acc[q]  = DOT2(SV2(qv, 3), d3, t);
            }
        }

        const float nd = sqrtf(sq);
#pragma unroll
        for (int q = 0; q < Q_; ++q) {
            const float nqv = nqBuf[b * Q_ + q];   // uniform -> s_load
            const float wqv = wqBuf[b * Q_ + q];
            const float denom = fmaxf(nqv * nd, 1e-8f);
            const float a = acc[q];
            // bins: [-1,-.5) [-.5,0) [0,.5) [.5,1) [1,1]; outside -> 0
            const float wv = (a < -denom)        ? 0.f
                           : (a < -0.5f * denom) ? w10
                           : (a < 0.f)           ? w11
                           : (a < 0.5f * denom)  ? w12
                           : (a < denom)         ? w13
                           : (a <= denom)        ? w14
                                                 : 0.f;
            total = fmaf(wqv, wv, total);
        }
    }

#pragma unroll
    for (int off = 32; off > 0; off >>= 1) total += __shfl_xor(total, off);
    if (lane == 0) wsum[w] = total;
    __syncthreads();
    if (tid == 0)
        atomicAdd(&score[b * D_ + d], wsum[0] + wsum[1]);
}

// ---------------------------------------------------------------------------
// Kernel 2 fallback (fp32, used only if ws can't hold the fp16 table):
// direct fp32 row streaming + fp32 queries in LDS (R15 structure).
// ---------------------------------------------------------------------------
__global__ __launch_bounds__(256, 4) void drmm_main_f32(
    const int* __restrict__ bq, const int* __restrict__ bdocs,
    const float* __restrict__ emb, const float* __restrict__ w1,
    const float* __restrict__ wqBuf, const float* __restrict__ nqBuf,
    float* __restrict__ score)
{
    const int ls = blockIdx.x;   // 0..3, 250 terms each
    const int d  = blockIdx.y;
    const int b  = blockIdx.z;
    const int tid  = threadIdx.x;
    const int lane = tid & 63;
    const int w    = tid >> 6;

    __shared__ float4 qt[Q_ * 76];    // chunks 0..74 row, 75 zeros
    __shared__ float wsum[4];

    for (int u = tid; u < Q_ * 76; u += 256) {
        const int q = u / 76;
        const int c = u - q * 76;
        float4 v = make_float4(0.f, 0.f, 0.f, 0.f);
        if (c < 75)
            v = *(const float4*)(emb + (size_t)bq[b * Q_ + q] * E_ + 4 * c);
        qt[u] = v;
    }
    __syncthreads();

    const int tok = bdocs[(b * D_ + d) * L_ + ls * 250 + min(tid, 249)];
    const float* drow = emb + (size_t)tok * E_;

    float acc[Q_];
#pragma unroll
    for (int q = 0; q < Q_; ++q) acc[q] = 0.f;
    float sqA = 0.f, sqB = 0.f;

#pragma unroll 9
    for (int g = 0; g < 37; ++g) {
        const float4 a  = *(const float4*)(drow + 8 * g);
        const float4 c4 = *(const float4*)(drow + 8 * g + 4);
        sqA = fmaf(a.x, a.x, fmaf(a.z, a.z, fmaf(c4.x, c4.x, fmaf(c4.z, c4.z, sqA))));
        sqB = fmaf(a.y, a.y, fmaf(a.w, a.w, fmaf(c4.y, c4.y, fmaf(c4.w, c4.w, sqB))));
#pragma unroll
        for (int q = 0; q < Q_; ++q) {
            const float4 qa = qt[q * 76 + 2 * g];
            const float4 qb = qt[q * 76 + 2 * g + 1];
            float t0 = fmaf(a.x, qa.x, fmaf(a.y, qa.y,
                       fmaf(a.z, qa.z, fmaf(a.w, qa.w, acc[q]))));
            acc[q]   = fmaf(c4.x, qb.x, fmaf(c4.y, qb.y,
                       fmaf(c4.z, qb.z, fmaf(c4.w, qb.w, t0))));
        }
    }
    {   // tail: elems 296..299
        const float4 a = *(const float4*)(drow + 296);
        sqA = fmaf(a.x, a.x, fmaf(a.z, a.z, sqA));
        sqB = fmaf(a.y, a.y, fmaf(a.w, a.w, sqB));
#pragma unroll
        for (int q = 0; q < Q_; ++q) {
            const float4 qa = qt[q * 76 + 74];
            acc[q] = fmaf(a.x, qa.x, fmaf(a.y, qa.y,
                     fmaf(a.z, qa.z, fmaf(a.w, qa.w, acc[q]))));
        }
    }

    float total = 0.f;
    if (tid < 250) {
        const float nd = sqrtf(sqA + sqB);
        const float w10 = w1[0], w11 = w1[1], w12 = w1[2],
                    w13 = w1[3], w14 = w1[4];
#pragma unroll
        for (int q = 0; q < Q_; ++q) {
            const float nqv = nqBuf[b * Q_ + q];
            const float wqv = wqBuf[b * Q_ + q];
            const float denom = fmaxf(nqv * nd, 1e-8f);
            const float a = acc[q];
            const float wv = (a < -denom)        ? 0.f
                           : (a < -0.5f * denom) ? w10
                           : (a < 0.f)           ? w11
                           : (a < 0.5f * denom)  ? w12
                           : (a < denom)         ? w13
                           : (a <= denom)        ? w14
                                                 : 0.f;
            total = fmaf(wqv, wv, total);
        }
    }

#pragma unroll
    for (int off = 32; off > 0; off >>= 1) total += __shfl_xor(total, off);
    if (lane == 0) wsum[w] = total;
    __syncthreads();
    if (tid == 0)
        atomicAdd(&score[b * D_ + d], wsum[0] + wsum[1] + wsum[2] + wsum[3]);
}

extern "C" void kernel_launch(void* const* d_in, const int* in_sizes, int n_in,
                              void* d_out, int out_size, void* d_ws, size_t ws_size,
                              hipStream_t stream)
{
    const int*   bq     = (const int*)d_in[0];
    const int*   bdocs  = (const int*)d_in[1];
    const float* emb    = (const float*)d_in[2];
    const float* gate_w = (const float*)d_in[3];
    const float* gate_b = (const float*)d_in[4];
    const float* w1     = (const float*)d_in[5];
    const float* b1     = (const float*)d_in[6];
    const float* w2     = (const float*)d_in[7];
    const float* b2     = (const float*)d_in[8];
    const float* out_w  = (const float*)d_in[9];
    const float* out_b  = (const float*)d_in[10];

    float* score = (float*)d_out;
    float* wqBuf = (float*)d_ws;              // 512 floats
    float* nqBuf = wqBuf + B_ * Q_;           // 512 floats (first 4 KiB)

    const size_t e16_off   = 4096;
    const size_t e16_bytes = (size_t)VOCAB_ * RP_ * sizeof(_Float16);  // 32 MB
    const bool useF16 = ws_size >= e16_off + e16_bytes;
    _Float16* emb16 = (_Float16*)((char*)d_ws + e16_off);

    if (useF16)
        drmm_cvt<<<dim3((CVU_ + 255) / 256), dim3(256), 0, stream>>>(emb, emb16);

    drmm_prep<<<dim3(B_), dim3(256), 0, stream>>>(
        bq, emb, gate_w, gate_b, b1, w2, b2, out_w, out_b, wqBuf, nqBuf, score);

    if (useF16)
        drmm_main_f16<<<dim3(NR_, D_, B_), dim3(128), 0, stream>>>(
            bq, bdocs, emb16, w1, wqBuf, nqBuf, score);
    else
        drmm_main_f32<<<dim3(4, D_, B_), dim3(256), 0, stream>>>(
            bq, bdocs, emb, w1, wqBuf, nqBuf, score);
}